// Round 5
// baseline (203.220 us; speedup 1.0000x reference)
//
#include <hip/hip_runtime.h>
#include <hip/hip_bf16.h>

#define AS1 __attribute__((address_space(1)))
#define AS3 __attribute__((address_space(3)))

typedef _Float16 half_t;
typedef __attribute__((ext_vector_type(8))) _Float16 f16x8;  // 8 f16 = 4 VGPRs
typedef __attribute__((ext_vector_type(4))) float f32x4;

static constexpr int Bsz = 4096;   // batch
static constexpr int INs = 512;    // input features
static constexpr int Hs  = 1024;   // hidden
static constexpr int BM  = 128;    // batch rows per block
static constexpr int BH  = 32;     // h-cols per block (x4 gates = 128 eff cols)
static constexpr int BK  = 64;     // K-tile

static constexpr size_t XN  = (size_t)Bsz * INs;      // 2,097,152
static constexpr size_t HXN = (size_t)Bsz * Hs;       // 4,194,304
static constexpr size_t WXN = (size_t)4 * Hs * INs;   // 2,097,152
static constexpr size_t WHN = (size_t)4 * Hs * Hs;    // 4,194,304
static constexpr size_t OFF_X  = 0;
static constexpr size_t OFF_HX = XN;
static constexpr size_t OFF_WX = XN + HXN;
static constexpr size_t OFF_WH = XN + HXN + WXN;
static constexpr size_t TOT    = XN + HXN + WXN + WHN; // 12,582,912 elems

// fp32 -> fp16 cast of the four matmul operands into workspace.
__global__ __launch_bounds__(256)
void cvt_kernel(const float* __restrict__ x, const float* __restrict__ hx,
                const float* __restrict__ wx, const float* __restrict__ wh,
                half_t* __restrict__ ws) {
  const size_t nthr = (size_t)gridDim.x * blockDim.x;
  for (size_t i8 = (size_t)blockIdx.x * blockDim.x + threadIdx.x;
       i8 < TOT / 8; i8 += nthr) {
    const size_t e = i8 * 8;
    const float* src; size_t off;
    if (e < OFF_HX)      { src = x;  off = e - OFF_X; }
    else if (e < OFF_WX) { src = hx; off = e - OFF_HX; }
    else if (e < OFF_WH) { src = wx; off = e - OFF_WX; }
    else                 { src = wh; off = e - OFF_WH; }
    const f32x4 a = *(const f32x4*)(src + off);
    const f32x4 b = *(const f32x4*)(src + off + 4);
    f16x8 o;
    o[0] = (half_t)a[0]; o[1] = (half_t)a[1]; o[2] = (half_t)a[2]; o[3] = (half_t)a[3];
    o[4] = (half_t)b[0]; o[5] = (half_t)b[1]; o[6] = (half_t)b[2]; o[7] = (half_t)b[3];
    *(f16x8*)(ws + e) = o;
  }
}

// Fused PhasedLSTM: gates = X*Wxh^T + hx*Whh^T + b via fp16 MFMA (fp32 accum),
// epilogue (time gate + LSTM) in pure fp32, np operation order.
// eff col c in [0,128): gate q=c/32, h=h0+c%32 -> W row q*H+h.
template <bool FROMWS>
__global__ __launch_bounds__(256, 2)
void plstm_gemm(const void* __restrict__ xin_,   // [B,IN]  f16(ws) or f32
                const float* __restrict__ timep, // [B]
                const void* __restrict__ hxp_,   // [B,H]
                const float* __restrict__ cxp,   // [B,H]
                const void* __restrict__ wxh_,   // [4H,IN]
                const float* __restrict__ biasp, // [4H]
                const void* __restrict__ whh_,   // [4H,H]
                const float* __restrict__ taup,  // [H]
                const float* __restrict__ sp,    // [H]
                const float* __restrict__ alphap,// [1]
                const float* __restrict__ rhop,  // [1]
                float* __restrict__ outp)        // [2,B,H] = hy ; cy
{
  // XOR-swizzled 16B-chunk layout: slot (row e, c8) holds global chunk c8^(e&7).
  __shared__ half_t As[BM * BK];    // 16 KB
  __shared__ half_t Bs[BM * BK];    // 16 KB

  const int tid  = threadIdx.x;
  const int w    = tid >> 6;
  const int lane = tid & 63;
  const int l15  = lane & 15;
  const int grp  = lane >> 4;

  const int m0 = blockIdx.x * BM;
  const int h0 = blockIdx.y * BH;

  f32x4 acc[2][8] = {};

  const int ldr = tid >> 3;      // 0..31
  const int ldc = tid & 7;       // 16B chunk col 0..7

  for (int phase = 0; phase < 2; ++phase) {
    const void* Ap = (phase == 0) ? xin_ : hxp_;
    const void* Wp = (phase == 0) ? wxh_ : whh_;
    const int Ka = (phase == 0) ? INs : Hs;

    for (int k0 = 0; k0 < Ka; k0 += BK) {
      #pragma unroll
      for (int i = 0; i < 4; ++i) {
        const int e    = i * 32 + ldr;
        const int gc8  = ldc ^ (e & 7);               // swizzle on global side
        const int wrow = (e >> 5) * Hs + h0 + (e & 31);
        if (FROMWS) {
          const half_t* ga = (const half_t*)Ap + (size_t)(m0 + e) * Ka + (k0 + gc8 * 8);
          __builtin_amdgcn_global_load_lds((AS1 void*)ga,
                                           (AS3 void*)(As + (e * 8 + ldc) * 8), 16, 0, 0);
          const half_t* gw = (const half_t*)Wp + (size_t)wrow * Ka + (k0 + gc8 * 8);
          __builtin_amdgcn_global_load_lds((AS1 void*)gw,
                                           (AS3 void*)(Bs + (e * 8 + ldc) * 8), 16, 0, 0);
        } else {
          const float* ga = (const float*)Ap + (size_t)(m0 + e) * Ka + (k0 + gc8 * 8);
          const f32x4 a0 = *(const f32x4*)ga, a1 = *(const f32x4*)(ga + 4);
          f16x8 pa;
          pa[0]=(half_t)a0[0]; pa[1]=(half_t)a0[1]; pa[2]=(half_t)a0[2]; pa[3]=(half_t)a0[3];
          pa[4]=(half_t)a1[0]; pa[5]=(half_t)a1[1]; pa[6]=(half_t)a1[2]; pa[7]=(half_t)a1[3];
          *(f16x8*)(As + (e * 8 + ldc) * 8) = pa;
          const float* gw = (const float*)Wp + (size_t)wrow * Ka + (k0 + gc8 * 8);
          const f32x4 b0 = *(const f32x4*)gw, b1 = *(const f32x4*)(gw + 4);
          f16x8 pb;
          pb[0]=(half_t)b0[0]; pb[1]=(half_t)b0[1]; pb[2]=(half_t)b0[2]; pb[3]=(half_t)b0[3];
          pb[4]=(half_t)b1[0]; pb[5]=(half_t)b1[1]; pb[6]=(half_t)b1[2]; pb[7]=(half_t)b1[3];
          *(f16x8*)(Bs + (e * 8 + ldc) * 8) = pb;
        }
      }
      __syncthreads();

      #pragma unroll
      for (int kk = 0; kk < 2; ++kk) {
        const int c8 = (kk * 4 + grp) ^ (l15 & 7);    // de-swizzle
        f16x8 af[2], bfr[8];
        #pragma unroll
        for (int mt = 0; mt < 2; ++mt) {
          const int e = w * 32 + mt * 16 + l15;       // e&7 == l15&7
          af[mt] = *(const f16x8*)(As + (e * 8 + c8) * 8);
        }
        #pragma unroll
        for (int nt = 0; nt < 8; ++nt) {
          const int e = nt * 16 + l15;
          bfr[nt] = *(const f16x8*)(Bs + (e * 8 + c8) * 8);
        }
        #pragma unroll
        for (int mt = 0; mt < 2; ++mt)
          #pragma unroll
          for (int nt = 0; nt < 8; ++nt)
            acc[mt][nt] = __builtin_amdgcn_mfma_f32_16x16x32_f16(
                af[mt], bfr[nt], acc[mt][nt], 0, 0, 0);
      }
      __syncthreads();
    }
  }

  // ---- fused epilogue: pure fp32, np operation order ----
  const float alphav = alphap[0];
  const float rhov   = rhop[0];
  const float rho_half = rhov * 0.5f;

  float sv[2], tauv[2], bi[2], bff[2], bg[2], bo[2];
  #pragma unroll
  for (int nt2 = 0; nt2 < 2; ++nt2) {
    const int h = h0 + nt2 * 16 + l15;
    sv[nt2]   = sp[h];
    tauv[nt2] = taup[h];
    bi[nt2]   = biasp[h];
    bff[nt2]  = biasp[Hs + h];
    bg[nt2]   = biasp[2 * Hs + h];
    bo[nt2]   = biasp[3 * Hs + h];
  }

  #pragma unroll
  for (int mt = 0; mt < 2; ++mt) {
    #pragma unroll
    for (int r = 0; r < 4; ++r) {
      // C/D layout (m89-verified): col = lane&15, row = grp*4 + reg
      const int brow = m0 + w * 32 + mt * 16 + grp * 4 + r;
      const float timev = timep[brow];
      #pragma unroll
      for (int nt2 = 0; nt2 < 2; ++nt2) {
        const int h = h0 + nt2 * 16 + l15;
        const float iv = acc[mt][0 + nt2][r] + bi[nt2];
        const float fv = acc[mt][2 + nt2][r] + bff[nt2];
        const float gv = acc[mt][4 + nt2][r] + bg[nt2];
        const float ov = acc[mt][6 + nt2][r] + bo[nt2];

        const float phi = fmodf(timev - sv[nt2], tauv[nt2]) / tauv[nt2];
        float kv;
        if (phi < rho_half)      kv = (2.0f * phi) / rhov;
        else if (phi < rhov)     kv = 2.0f - (2.0f * phi) / rhov;
        else                     kv = alphav * phi;

        const float cxv = cxp[(size_t)brow * Hs + h];
        const float ft = 1.0f / (1.0f + expf(-(fv + 1.0f - kv)));
        const float it = kv / (1.0f + expf(-iv));
        const float gt = tanhf(gv) * kv;
        const float ot = kv / (1.0f + expf(-ov));
        const float cy = ft * cxv + it * gt;
        const float hy = ot * tanhf(cy);

        outp[(size_t)brow * Hs + h] = hy;
        outp[(size_t)Bsz * Hs + (size_t)brow * Hs + h] = cy;
      }
    }
  }
}

extern "C" void kernel_launch(void* const* d_in, const int* in_sizes, int n_in,
                              void* d_out, int out_size, void* d_ws, size_t ws_size,
                              hipStream_t stream) {
  (void)in_sizes; (void)n_in; (void)out_size;
  const float* xin   = (const float*)d_in[0];
  const float* timep = (const float*)d_in[1];
  const float* hxp   = (const float*)d_in[2];
  const float* cxp   = (const float*)d_in[3];
  const float* wxh   = (const float*)d_in[4];
  const float* biasp = (const float*)d_in[5];
  const float* whh   = (const float*)d_in[6];
  const float* taup  = (const float*)d_in[7];
  const float* sp    = (const float*)d_in[8];
  const float* alphap= (const float*)d_in[9];
  const float* rhop  = (const float*)d_in[10];
  float* outp = (float*)d_out;

  dim3 grid(Bsz / BM, Hs / BH);   // 32 x 32 = 1024 blocks
  if (ws_size >= TOT * sizeof(half_t)) {
    half_t* ws = (half_t*)d_ws;
    cvt_kernel<<<2048, 256, 0, stream>>>(xin, hxp, wxh, whh, ws);
    plstm_gemm<true><<<grid, 256, 0, stream>>>(
        ws + OFF_X, timep, ws + OFF_HX, cxp, ws + OFF_WX, biasp, ws + OFF_WH,
        taup, sp, alphap, rhop, outp);
  } else {
    plstm_gemm<false><<<grid, 256, 0, stream>>>(
        xin, timep, hxp, cxp, wxh, biasp, whh,
        taup, sp, alphap, rhop, outp);
  }
}